// Round 7
// baseline (208.148 us; speedup 1.0000x reference)
//
#include <hip/hip_runtime.h>
#include <stdint.h>

#define N_NODES_C 20000
#define N_EDGES_C 320000
#define NUM_RELS_C 16
#define FEAT_C 256
#define CAP_LOG2 6           // 64 slots per dst in direct-bucket fast path
#define WS_FAST_BYTES  186497152ULL   // fast path, no bitmap
#define WS_FAST2_BYTES 186577152ULL   // fast path + used-bitmap (store masking)

typedef __bf16 bf16_t;
typedef __bf16 bf16x8 __attribute__((ext_vector_type(8)));
typedef __bf16 bf16x4 __attribute__((ext_vector_type(4)));
typedef float f32x4 __attribute__((ext_vector_type(4)));

__device__ __forceinline__ void async_load16(const void* g, void* l) {
  __builtin_amdgcn_global_load_lds(
      (__attribute__((address_space(1))) void*)const_cast<void*>(g),
      (__attribute__((address_space(3))) void*)l, 16, 0, 0);
}

// ================= FAST PATH (4 dispatches) =================
// prep_fast: [0,5000) h->bf16 | [5000,5256) W transpose via LDS tile |
// [5256,6506) direct-bucket edges into 64-slot bins + (r,src) used-bitmap.
__global__ void prep_fast_kernel(const float* __restrict__ h, bf16_t* __restrict__ hB,
                                 const float* __restrict__ W, bf16_t* __restrict__ Wt,
                                 const int* __restrict__ dst, const int* __restrict__ src,
                                 const int* __restrict__ rel, const float* __restrict__ norm,
                                 int* __restrict__ cnt, int2* __restrict__ bkt,
                                 unsigned* __restrict__ used) {
  int b = blockIdx.x;
  int t = threadIdx.x;
  if (b < 5000) {
    int i = (b * 256 + t) * 4;
    float4 v = *(const float4*)(h + i);
    bf16x4 o = { (bf16_t)v.x, (bf16_t)v.y, (bf16_t)v.z, (bf16_t)v.w };
    *(bf16x4*)(hB + i) = o;
  } else if (b < 5256) {
    // 64(i) x 64(o) tile transpose: W[r][i][o] f32 -> Wt[r][o][i] bf16
    __shared__ bf16_t lds[64][66];
    int b2 = b - 5000;
    int r  = b2 >> 4;
    int i0 = ((b2 >> 2) & 3) << 6;
    int o0 = (b2 & 3) << 6;
    int tx = t & 15;
    int ty = t >> 4;
#pragma unroll
    for (int pass = 0; pass < 4; ++pass) {
      int il = ty + pass * 16;
      float4 v = *(const float4*)(W + (r << 16) + ((i0 + il) << 8) + o0 + tx * 4);
      lds[tx * 4 + 0][il] = (bf16_t)v.x;
      lds[tx * 4 + 1][il] = (bf16_t)v.y;
      lds[tx * 4 + 2][il] = (bf16_t)v.z;
      lds[tx * 4 + 3][il] = (bf16_t)v.w;
    }
    __syncthreads();
#pragma unroll
    for (int pass = 0; pass < 4; ++pass) {
      int ol = ty + pass * 16;
      bf16x4 pk = { lds[ol][tx * 4 + 0], lds[ol][tx * 4 + 1],
                    lds[ol][tx * 4 + 2], lds[ol][tx * 4 + 3] };
      *(bf16x4*)(Wt + (r << 16) + ((o0 + ol) << 8) + i0 + tx * 4) = pk;
    }
  } else {
    int e = (b - 5256) * 256 + t;
    if (e < N_EDGES_C) {
      int d = dst[e];
      int s = src[e];
      int r = rel[e];
      int pos = (d << CAP_LOG2) + atomicAdd(&cnt[d], 1);
      int2 pk;
      pk.x = s | (r << 16);
      pk.y = __float_as_int(norm[e]);
      bkt[pos] = pk;
      if (used) atomicOr(&used[s], 1u << r);
    }
  }
}

// ================= SLOW PATH (known-good 6-dispatch CSR chain) =================
__global__ void prep_kernel(const float* __restrict__ h, bf16_t* __restrict__ hB,
                            const float* __restrict__ W, bf16_t* __restrict__ Wt,
                            const int* __restrict__ dst, int* __restrict__ dcur) {
  int b = blockIdx.x;
  int t = threadIdx.x;
  if (b < 5000) {
    int i = (b * 256 + t) * 4;
    float4 v = *(const float4*)(h + i);
    bf16x4 o = { (bf16_t)v.x, (bf16_t)v.y, (bf16_t)v.z, (bf16_t)v.w };
    *(bf16x4*)(hB + i) = o;
  } else if (b < 9096) {
    int g = (b - 5000) * 256 + t;
    int i = g & 255;
    int o = (g >> 8) & 255;
    int r = g >> 16;
    Wt[(r << 16) + (o << 8) + i] = (bf16_t)W[(r << 16) + (i << 8) + o];
  } else {
    int e = (b - 9096) * 256 + t;
    if (e < N_EDGES_C) atomicAdd(&dcur[dst[e]], 1);
  }
}

__global__ void scan_dst_kernel(int* __restrict__ dcur, int* __restrict__ dstart) {
  __shared__ unsigned short cnt[20224];
  __shared__ int wsum[4];
  const int CH = 79;
  int t = threadIdx.x;
  int base = t * CH;
  int sum = 0;
  for (int i = 0; i < CH; ++i) {
    int idx = base + i;
    int c = (idx < N_NODES_C) ? dcur[idx] : 0;
    cnt[idx] = (unsigned short)c;
    sum += c;
  }
  int v = sum;
#pragma unroll
  for (int off = 1; off < 64; off <<= 1) {
    int u = __shfl_up(v, off);
    if ((t & 63) >= off) v += u;
  }
  if ((t & 63) == 63) wsum[t >> 6] = v;
  __syncthreads();
  int add = 0;
  for (int w = 0; w < (t >> 6); ++w) add += wsum[w];
  int run = v - sum + add;
  for (int i = 0; i < CH; ++i) {
    int idx = base + i;
    if (idx < N_NODES_C) {
      int c = cnt[idx];
      dstart[idx] = run;
      dcur[idx] = run;
      run += c;
    }
  }
  if (t == 0) dstart[N_NODES_C] = N_EDGES_C;
}

__global__ void bucket_dst_kernel(const int* __restrict__ dst, const int* __restrict__ src,
                                  const int* __restrict__ rel, const float* __restrict__ norm,
                                  int* __restrict__ dcur, int2* __restrict__ bkt) {
  int e = blockIdx.x * blockDim.x + threadIdx.x;
  if (e < N_EDGES_C) {
    int pos = atomicAdd(&dcur[dst[e]], 1);
    int2 pk;
    pk.x = src[e] | (rel[e] << 16);
    pk.y = __float_as_int(norm[e]);
    bkt[pos] = pk;
  }
}

// ---- Phase A: R2 tile/frag math + counted-vmcnt pipeline, write-ceiling-bound.
// NEW: store masking — only ~63% of Tb rows (those with an actual (rel,src) edge)
// are ever read by aggregate; skip stores for unused rows (used-bitmap, bit r of
// used[row]). WRITE_SIZE 160 MB -> ~101 MB.
__global__ __launch_bounds__(256) void gemm_t_kernel(
    const bf16_t* __restrict__ hB, const bf16_t* __restrict__ Wt,
    bf16_t* __restrict__ Tb, const unsigned* __restrict__ used) {
  int bx = blockIdx.x;
  int sub = bx & 31;
  int m0 = (bx >> 5) << 7;
  int r  = sub >> 1;
  int n0 = (sub & 1) << 7;

  __shared__ bf16_t Asm[3 * 128 * 32];   // 24 KB (triple-buffered)
  __shared__ bf16_t Bsm[3 * 128 * 32];   // 24 KB

  int tid = threadIdx.x;
  int lrow = tid >> 2;
  int pch = tid & 3;
  int rA0 = lrow, rA1 = lrow + 64;
  int lc0 = pch ^ ((rA0 >> 1) & 3);
  int lc1 = pch ^ ((rA1 >> 1) & 3);
  int gr0 = m0 + rA0; if (gr0 > N_NODES_C - 1) gr0 = N_NODES_C - 1;
  int gr1 = m0 + rA1; if (gr1 > N_NODES_C - 1) gr1 = N_NODES_C - 1;
  const char* gA0 = (const char*)(hB + (size_t)gr0 * FEAT_C) + lc0 * 16;
  const char* gA1 = (const char*)(hB + (size_t)gr1 * FEAT_C) + lc1 * 16;
  const char* gB0 = (const char*)(Wt + ((size_t)r * 256 + n0 + rA0) * FEAT_C) + lc0 * 16;
  const char* gB1 = (const char*)(Wt + ((size_t)r * 256 + n0 + rA1) * FEAT_C) + lc1 * 16;

  int wave = tid >> 6;
  int lane = tid & 63;
  int lq = lane >> 4;
  int lr = lane & 15;
  int wm = (wave >> 1) * 64;
  int wn = (wave & 1) * 64;
  int pc8 = (lq ^ ((lr >> 1) & 3)) * 8;

  f32x4 acc[4][4] = {};

#define STAGE(buf, t)                                             \
  do {                                                            \
    int kb_ = (t) * 64;                                           \
    char* aB_ = (char*)Asm + (buf) * 8192 + wave * 1024;          \
    char* bB_ = (char*)Bsm + (buf) * 8192 + wave * 1024;          \
    async_load16(gA0 + kb_, aB_);                                 \
    async_load16(gA1 + kb_, aB_ + 4096);                          \
    async_load16(gB0 + kb_, bB_);                                 \
    async_load16(gB1 + kb_, bB_ + 4096);                          \
  } while (0)

  STAGE(0, 0);
  STAGE(1, 1);

#pragma unroll
  for (int kk = 0; kk < 8; ++kk) {
    if (kk < 7) asm volatile("s_waitcnt vmcnt(4)" ::: "memory");
    else        asm volatile("s_waitcnt vmcnt(0)" ::: "memory");
    __builtin_amdgcn_s_barrier();
    __builtin_amdgcn_sched_barrier(0);
    const bf16_t* Ac = Asm + (kk % 3) * 4096;
    const bf16_t* Bc = Bsm + (kk % 3) * 4096;
    bf16x8 af[4], bfr[4];
#pragma unroll
    for (int mt = 0; mt < 4; ++mt) {
      int row = wm + mt * 16 + lr;
      af[mt] = *(const bf16x8*)&Ac[row * 32 + pc8];
    }
#pragma unroll
    for (int nt2 = 0; nt2 < 4; ++nt2) {
      int row = wn + nt2 * 16 + lr;
      bfr[nt2] = *(const bf16x8*)&Bc[row * 32 + pc8];
    }
    if (kk < 6) STAGE((kk + 2) % 3, kk + 2);
#pragma unroll
    for (int mt = 0; mt < 4; ++mt)
#pragma unroll
      for (int nt2 = 0; nt2 < 4; ++nt2)
        acc[mt][nt2] = __builtin_amdgcn_mfma_f32_16x16x32_bf16(af[mt], bfr[nt2], acc[mt][nt2], 0, 0, 0);
  }
#undef STAGE

  // Prefetch this lane's 8 used-bits (rows fixed per lane) before the store burst.
  int odd0 = lr & 1;
  unsigned um[4][2];
  if (used) {
#pragma unroll
    for (int mt = 0; mt < 4; ++mt)
#pragma unroll
      for (int a = 0; a < 2; ++a) {
        int row = m0 + wm + mt * 16 + lq * 4 + a * 2 + odd0;
        um[mt][a] = (row < N_NODES_C) ? used[row] : 0u;
      }
  }

  // Epilogue: 16B/lane stores via parity-pair shfl_xor merge; predicated on used-bit.
#pragma unroll
  for (int mt = 0; mt < 4; ++mt) {
#pragma unroll
    for (int a = 0; a < 2; ++a) {
      int rg0 = a * 2, rg1 = rg0 + 1;
      union { bf16x4 v; long long u; } q0, q1;
      q0.v = (bf16x4){ (bf16_t)acc[mt][0][rg0], (bf16_t)acc[mt][1][rg0],
                       (bf16_t)acc[mt][2][rg0], (bf16_t)acc[mt][3][rg0] };
      q1.v = (bf16x4){ (bf16_t)acc[mt][0][rg1], (bf16_t)acc[mt][1][rg1],
                       (bf16_t)acc[mt][2][rg1], (bf16_t)acc[mt][3][rg1] };
      int odd = lr & 1;
      long long send = odd ? q0.u : q1.u;
      long long got = __shfl_xor(send, 1);
      union { bf16x8 v; long long u[2]; } w;
      w.u[0] = odd ? got : q0.u;
      w.u[1] = odd ? q1.u : got;
      int rg = rg0 + odd;
      int row = m0 + wm + mt * 16 + lq * 4 + rg;
      bool go = (row < N_NODES_C);
      if (go && used) go = (um[mt][a] >> r) & 1u;
      if (go) {
        int pos = n0 + wn + ((lr >> 1) << 3);
        *(bf16x8*)(Tb + (((size_t)r * N_NODES_C + row) << 8) + pos) = w.v;
      }
    }
  }
}

// ---- Phase B: per-dst gather-reduce, half-wave per edge, 16B/lane, unroll x4 ----
template <int MODE>
__global__ __launch_bounds__(256) void aggregate_kernel(
    const bf16_t* __restrict__ Tb, const int* __restrict__ meta,
    const int2* __restrict__ bkt, float* __restrict__ out) {
  int tid = threadIdx.x;
  int d = blockIdx.x * 4 + (tid >> 6);
  int lane = tid & 63;
  int h = lane >> 5;
  int l5 = lane & 31;
  int p0, p1;
  if (MODE == 0) { p0 = meta[d]; p1 = meta[d + 1]; }
  else           { p0 = d << CAP_LOG2; p1 = p0 + meta[d]; }
  int boff = l5 << 4;
  float A0[8] = {}, A1[8] = {}, A2[8] = {}, A3[8] = {};
  int p = p0 + h;
  for (; p + 6 < p1; p += 8) {
    int2 e0 = bkt[p];
    int2 e1 = bkt[p + 2];
    int2 e2 = bkt[p + 4];
    int2 e3 = bkt[p + 6];
    bf16x8 v0 = *(const bf16x8*)((const char*)(Tb + (((size_t)(e0.x >> 16) * N_NODES_C + (e0.x & 0xFFFF)) << 8)) + boff);
    bf16x8 v1 = *(const bf16x8*)((const char*)(Tb + (((size_t)(e1.x >> 16) * N_NODES_C + (e1.x & 0xFFFF)) << 8)) + boff);
    bf16x8 v2 = *(const bf16x8*)((const char*)(Tb + (((size_t)(e2.x >> 16) * N_NODES_C + (e2.x & 0xFFFF)) << 8)) + boff);
    bf16x8 v3 = *(const bf16x8*)((const char*)(Tb + (((size_t)(e3.x >> 16) * N_NODES_C + (e3.x & 0xFFFF)) << 8)) + boff);
    float n0 = __int_as_float(e0.y), n1 = __int_as_float(e1.y);
    float n2 = __int_as_float(e2.y), n3 = __int_as_float(e3.y);
#pragma unroll
    for (int j = 0; j < 8; ++j) {
      A0[j] += (float)v0[j] * n0;
      A1[j] += (float)v1[j] * n1;
      A2[j] += (float)v2[j] * n2;
      A3[j] += (float)v3[j] * n3;
    }
  }
  for (; p < p1; p += 2) {
    int2 e0 = bkt[p];
    bf16x8 v0 = *(const bf16x8*)((const char*)(Tb + (((size_t)(e0.x >> 16) * N_NODES_C + (e0.x & 0xFFFF)) << 8)) + boff);
    float n0 = __int_as_float(e0.y);
#pragma unroll
    for (int j = 0; j < 8; ++j) A0[j] += (float)v0[j] * n0;
  }
  float s[8];
#pragma unroll
  for (int j = 0; j < 8; ++j) {
    s[j] = (A0[j] + A1[j]) + (A2[j] + A3[j]);
    s[j] += __shfl_xor(s[j], 32);
  }
  if (h == 0) {
    int g64 = (l5 >> 3) << 6;
    int lr4 = (l5 << 1) & 15;
    float* o = out + (size_t)d * FEAT_C + g64 + lr4;
#pragma unroll
    for (int j = 0; j < 4; ++j) {
      float2 w = { s[j], s[j + 4] };
      *(float2*)(o + j * 16) = w;
    }
  }
}

extern "C" void kernel_launch(void* const* d_in, const int* in_sizes, int n_in,
                              void* d_out, int out_size, void* d_ws, size_t ws_size,
                              hipStream_t stream) {
  const float* h    = (const float*)d_in[0];
  const float* W    = (const float*)d_in[1];
  const float* norm = (const float*)d_in[2];
  const int*   src  = (const int*)d_in[3];
  const int*   dst  = (const int*)d_in[4];
  const int*   rel  = (const int*)d_in[5];
  float* out = (float*)d_out;

  char* ws = (char*)d_ws;
  bf16_t* hB   = (bf16_t*)ws;                          // 10,240,000 B
  bf16_t* Wt   = (bf16_t*)(ws + 10240000);             //  2,097,152 B
  bf16_t* Tb   = (bf16_t*)(ws + 12337152);             // 163,840,000 B -> 176,177,152

  if (ws_size >= WS_FAST2_BYTES) {
    // ---- fast path + store-mask bitmap ----
    int* cnt       = (int*)(ws + 176177152);           // 80,000 B
    unsigned* used = (unsigned*)(ws + 176257152);      // 80,000 B
    int2* bkt      = (int2*)(ws + 176337152);          // 10,240,000 B -> 186,577,152
    hipMemsetAsync(cnt, 0, 160000, stream);            // zeroes cnt + used (contiguous)
    prep_fast_kernel<<<6506, 256, 0, stream>>>(h, hB, W, Wt, dst, src, rel, norm, cnt, bkt, used);
    gemm_t_kernel<<<dim3(157 * 32, 1, 1), 256, 0, stream>>>(hB, Wt, Tb, used);
    aggregate_kernel<1><<<5000, 256, 0, stream>>>(Tb, cnt, bkt, out);
  } else if (ws_size >= WS_FAST_BYTES) {
    // ---- fast path, no bitmap ----
    int* cnt  = (int*)(ws + 176177152);                // 80,000 B
    int2* bkt = (int2*)(ws + 176257152);               // 10,240,000 B -> 186,497,152
    hipMemsetAsync(cnt, 0, N_NODES_C * sizeof(int), stream);
    prep_fast_kernel<<<6506, 256, 0, stream>>>(h, hB, W, Wt, dst, src, rel, norm, cnt, bkt, nullptr);
    gemm_t_kernel<<<dim3(157 * 32, 1, 1), 256, 0, stream>>>(hB, Wt, Tb, nullptr);
    aggregate_kernel<1><<<5000, 256, 0, stream>>>(Tb, cnt, bkt, out);
  } else {
    // ---- slow path: known-good CSR chain ----
    int* dstart  = (int*)(ws + 176177152);             // 80,016 B
    int* dcur    = (int*)(ws + 176257168);             // 80,000 B
    int2* bkt    = (int2*)(ws + 176337168);            // 2,560,000 B -> ~178.9 MB
    hipMemsetAsync(dcur, 0, N_NODES_C * sizeof(int), stream);
    prep_kernel<<<10346, 256, 0, stream>>>(h, hB, W, Wt, dst, dcur);
    scan_dst_kernel<<<1, 256, 0, stream>>>(dcur, dstart);
    bucket_dst_kernel<<<1250, 256, 0, stream>>>(dst, src, rel, norm, dcur, bkt);
    gemm_t_kernel<<<dim3(157 * 32, 1, 1), 256, 0, stream>>>(hB, Wt, Tb, nullptr);
    aggregate_kernel<0><<<5000, 256, 0, stream>>>(Tb, dstart, bkt, out);
  }
}

// Round 8
// 184.766 us; speedup vs baseline: 1.1265x; 1.1265x over previous
//
#include <hip/hip_runtime.h>
#include <stdint.h>

#define N_NODES_C 20000
#define N_EDGES_C 320000
#define NUM_RELS_C 16
#define FEAT_C 256
#define CAP_LOG2 6           // 64 slots per dst in direct-bucket fast path
#define GEMM_BLOCKS 5024     // 157 m-tiles * 32 (r*2 + n_half)
#define WS_FAST_BYTES 186497152ULL

typedef __bf16 bf16_t;
typedef __bf16 bf16x8 __attribute__((ext_vector_type(8)));
typedef __bf16 bf16x4 __attribute__((ext_vector_type(4)));
typedef float f32x4 __attribute__((ext_vector_type(4)));

__device__ __forceinline__ void async_load16(const void* g, void* l) {
  __builtin_amdgcn_global_load_lds(
      (__attribute__((address_space(1))) void*)const_cast<void*>(g),
      (__attribute__((address_space(3))) void*)l, 16, 0, 0);
}

// ================= FAST PATH (3 dispatches) =================
// prep_fast: [0,5000) h->bf16 | [5000,5256) W transpose via LDS tile |
// [5256,5335) zero cnt (replaces the hipMemsetAsync dispatch).
__global__ void prep_fast_kernel(const float* __restrict__ h, bf16_t* __restrict__ hB,
                                 const float* __restrict__ W, bf16_t* __restrict__ Wt,
                                 int* __restrict__ cnt) {
  int b = blockIdx.x;
  int t = threadIdx.x;
  if (b < 5000) {
    int i = (b * 256 + t) * 4;
    float4 v = *(const float4*)(h + i);
    bf16x4 o = { (bf16_t)v.x, (bf16_t)v.y, (bf16_t)v.z, (bf16_t)v.w };
    *(bf16x4*)(hB + i) = o;
  } else if (b < 5256) {
    // 64(i) x 64(o) tile transpose: W[r][i][o] f32 -> Wt[r][o][i] bf16
    __shared__ bf16_t lds[64][66];   // odd-dword row stride -> conflict-free
    int b2 = b - 5000;
    int r  = b2 >> 4;
    int i0 = ((b2 >> 2) & 3) << 6;
    int o0 = (b2 & 3) << 6;
    int tx = t & 15;
    int ty = t >> 4;
#pragma unroll
    for (int pass = 0; pass < 4; ++pass) {
      int il = ty + pass * 16;
      float4 v = *(const float4*)(W + (r << 16) + ((i0 + il) << 8) + o0 + tx * 4);
      lds[tx * 4 + 0][il] = (bf16_t)v.x;
      lds[tx * 4 + 1][il] = (bf16_t)v.y;
      lds[tx * 4 + 2][il] = (bf16_t)v.z;
      lds[tx * 4 + 3][il] = (bf16_t)v.w;
    }
    __syncthreads();
#pragma unroll
    for (int pass = 0; pass < 4; ++pass) {
      int ol = ty + pass * 16;
      bf16x4 pk = { lds[ol][tx * 4 + 0], lds[ol][tx * 4 + 1],
                    lds[ol][tx * 4 + 2], lds[ol][tx * 4 + 3] };
      *(bf16x4*)(Wt + (r << 16) + ((o0 + ol) << 8) + i0 + tx * 4) = pk;
    }
  } else {
    int idx = (b - 5256) * 256 + t;
    if (idx < N_NODES_C) cnt[idx] = 0;
  }
}

// ================= SLOW PATH (known-good 6-dispatch CSR chain) =================
__global__ void prep_kernel(const float* __restrict__ h, bf16_t* __restrict__ hB,
                            const float* __restrict__ W, bf16_t* __restrict__ Wt,
                            const int* __restrict__ dst, int* __restrict__ dcur) {
  int b = blockIdx.x;
  int t = threadIdx.x;
  if (b < 5000) {
    int i = (b * 256 + t) * 4;
    float4 v = *(const float4*)(h + i);
    bf16x4 o = { (bf16_t)v.x, (bf16_t)v.y, (bf16_t)v.z, (bf16_t)v.w };
    *(bf16x4*)(hB + i) = o;
  } else if (b < 9096) {
    int g = (b - 5000) * 256 + t;
    int i = g & 255;
    int o = (g >> 8) & 255;
    int r = g >> 16;
    Wt[(r << 16) + (o << 8) + i] = (bf16_t)W[(r << 16) + (i << 8) + o];
  } else {
    int e = (b - 9096) * 256 + t;
    if (e < N_EDGES_C) atomicAdd(&dcur[dst[e]], 1);
  }
}

__global__ void scan_dst_kernel(int* __restrict__ dcur, int* __restrict__ dstart) {
  __shared__ unsigned short cnt[20224];
  __shared__ int wsum[4];
  const int CH = 79;
  int t = threadIdx.x;
  int base = t * CH;
  int sum = 0;
  for (int i = 0; i < CH; ++i) {
    int idx = base + i;
    int c = (idx < N_NODES_C) ? dcur[idx] : 0;
    cnt[idx] = (unsigned short)c;
    sum += c;
  }
  int v = sum;
#pragma unroll
  for (int off = 1; off < 64; off <<= 1) {
    int u = __shfl_up(v, off);
    if ((t & 63) >= off) v += u;
  }
  if ((t & 63) == 63) wsum[t >> 6] = v;
  __syncthreads();
  int add = 0;
  for (int w = 0; w < (t >> 6); ++w) add += wsum[w];
  int run = v - sum + add;
  for (int i = 0; i < CH; ++i) {
    int idx = base + i;
    if (idx < N_NODES_C) {
      int c = cnt[idx];
      dstart[idx] = run;
      dcur[idx] = run;
      run += c;
    }
  }
  if (t == 0) dstart[N_NODES_C] = N_EDGES_C;
}

__global__ void bucket_dst_kernel(const int* __restrict__ dst, const int* __restrict__ src,
                                  const int* __restrict__ rel, const float* __restrict__ norm,
                                  int* __restrict__ dcur, int2* __restrict__ bkt) {
  int e = blockIdx.x * blockDim.x + threadIdx.x;
  if (e < N_EDGES_C) {
    int pos = atomicAdd(&dcur[dst[e]], 1);
    int2 pk;
    pk.x = src[e] | (rel[e] << 16);
    pk.y = __float_as_int(norm[e]);
    bkt[pos] = pk;
  }
}

// ---- Phase A (+ hidden bucket): R2 tile/frag math + counted-vmcnt pipeline.
// Gemm is structure-bound at ~62 µs (R1/R2/R4/R7: barriers, depth, FETCH, store
// width, WRITE bytes all neutral) — frozen. Blocks [GEMM_BLOCKS, +1250) instead
// run the edge direct-bucket scatter, filling CUs in the gemm's dispatch tail.
__global__ __launch_bounds__(256) void gemm_bucket_kernel(
    const bf16_t* __restrict__ hB, const bf16_t* __restrict__ Wt,
    bf16_t* __restrict__ Tb,
    const int* __restrict__ dst, const int* __restrict__ src,
    const int* __restrict__ rel, const float* __restrict__ norm,
    int* __restrict__ cnt, int2* __restrict__ bkt) {
  int bx = blockIdx.x;
  int tid = threadIdx.x;

  if (bx >= GEMM_BLOCKS) {
    // ---- bucket branch: direct-bin scatter (cnt zeroed by prep dispatch) ----
    int e = (bx - GEMM_BLOCKS) * 256 + tid;
    if (e < N_EDGES_C) {
      int d = dst[e];
      int pos = (d << CAP_LOG2) + atomicAdd(&cnt[d], 1);
      int2 pk;
      pk.x = src[e] | (rel[e] << 16);
      pk.y = __float_as_int(norm[e]);
      bkt[pos] = pk;
    }
    return;
  }

  int sub = bx & 31;
  int m0 = (bx >> 5) << 7;
  int r  = sub >> 1;
  int n0 = (sub & 1) << 7;

  __shared__ bf16_t Asm[3 * 128 * 32];   // 24 KB (triple-buffered)
  __shared__ bf16_t Bsm[3 * 128 * 32];   // 24 KB

  int lrow = tid >> 2;
  int pch = tid & 3;
  int rA0 = lrow, rA1 = lrow + 64;
  int lc0 = pch ^ ((rA0 >> 1) & 3);
  int lc1 = pch ^ ((rA1 >> 1) & 3);
  int gr0 = m0 + rA0; if (gr0 > N_NODES_C - 1) gr0 = N_NODES_C - 1;
  int gr1 = m0 + rA1; if (gr1 > N_NODES_C - 1) gr1 = N_NODES_C - 1;
  const char* gA0 = (const char*)(hB + (size_t)gr0 * FEAT_C) + lc0 * 16;
  const char* gA1 = (const char*)(hB + (size_t)gr1 * FEAT_C) + lc1 * 16;
  const char* gB0 = (const char*)(Wt + ((size_t)r * 256 + n0 + rA0) * FEAT_C) + lc0 * 16;
  const char* gB1 = (const char*)(Wt + ((size_t)r * 256 + n0 + rA1) * FEAT_C) + lc1 * 16;

  int wave = tid >> 6;
  int lane = tid & 63;
  int lq = lane >> 4;
  int lr = lane & 15;
  int wm = (wave >> 1) * 64;
  int wn = (wave & 1) * 64;
  int pc8 = (lq ^ ((lr >> 1) & 3)) * 8;

  f32x4 acc[4][4] = {};

#define STAGE(buf, t)                                             \
  do {                                                            \
    int kb_ = (t) * 64;                                           \
    char* aB_ = (char*)Asm + (buf) * 8192 + wave * 1024;          \
    char* bB_ = (char*)Bsm + (buf) * 8192 + wave * 1024;          \
    async_load16(gA0 + kb_, aB_);                                 \
    async_load16(gA1 + kb_, aB_ + 4096);                          \
    async_load16(gB0 + kb_, bB_);                                 \
    async_load16(gB1 + kb_, bB_ + 4096);                          \
  } while (0)

  STAGE(0, 0);
  STAGE(1, 1);

#pragma unroll
  for (int kk = 0; kk < 8; ++kk) {
    if (kk < 7) asm volatile("s_waitcnt vmcnt(4)" ::: "memory");
    else        asm volatile("s_waitcnt vmcnt(0)" ::: "memory");
    __builtin_amdgcn_s_barrier();
    __builtin_amdgcn_sched_barrier(0);
    const bf16_t* Ac = Asm + (kk % 3) * 4096;
    const bf16_t* Bc = Bsm + (kk % 3) * 4096;
    bf16x8 af[4], bfr[4];
#pragma unroll
    for (int mt = 0; mt < 4; ++mt) {
      int row = wm + mt * 16 + lr;
      af[mt] = *(const bf16x8*)&Ac[row * 32 + pc8];
    }
#pragma unroll
    for (int nt2 = 0; nt2 < 4; ++nt2) {
      int row = wn + nt2 * 16 + lr;
      bfr[nt2] = *(const bf16x8*)&Bc[row * 32 + pc8];
    }
    if (kk < 6) STAGE((kk + 2) % 3, kk + 2);
#pragma unroll
    for (int mt = 0; mt < 4; ++mt)
#pragma unroll
      for (int nt2 = 0; nt2 < 4; ++nt2)
        acc[mt][nt2] = __builtin_amdgcn_mfma_f32_16x16x32_bf16(af[mt], bfr[nt2], acc[mt][nt2], 0, 0, 0);
  }
#undef STAGE

  // Epilogue: 16B/lane stores via parity-pair shfl_xor merge (layout unchanged).
#pragma unroll
  for (int mt = 0; mt < 4; ++mt) {
#pragma unroll
    for (int a = 0; a < 2; ++a) {
      int rg0 = a * 2, rg1 = rg0 + 1;
      union { bf16x4 v; long long u; } q0, q1;
      q0.v = (bf16x4){ (bf16_t)acc[mt][0][rg0], (bf16_t)acc[mt][1][rg0],
                       (bf16_t)acc[mt][2][rg0], (bf16_t)acc[mt][3][rg0] };
      q1.v = (bf16x4){ (bf16_t)acc[mt][0][rg1], (bf16_t)acc[mt][1][rg1],
                       (bf16_t)acc[mt][2][rg1], (bf16_t)acc[mt][3][rg1] };
      int odd = lr & 1;
      long long send = odd ? q0.u : q1.u;
      long long got = __shfl_xor(send, 1);
      union { bf16x8 v; long long u[2]; } w;
      w.u[0] = odd ? got : q0.u;
      w.u[1] = odd ? q1.u : got;
      int rg = rg0 + odd;
      int row = m0 + wm + mt * 16 + lq * 4 + rg;
      if (row < N_NODES_C) {
        int pos = n0 + wn + ((lr >> 1) << 3);
        *(bf16x8*)(Tb + (((size_t)r * N_NODES_C + row) << 8) + pos) = w.v;
      }
    }
  }
}

// ---- Phase B: per-dst gather-reduce, half-wave per edge, 16B/lane, 8-deep batches ----
template <int MODE>
__global__ __launch_bounds__(256) void aggregate_kernel(
    const bf16_t* __restrict__ Tb, const int* __restrict__ meta,
    const int2* __restrict__ bkt, float* __restrict__ out) {
  int tid = threadIdx.x;
  int d = blockIdx.x * 4 + (tid >> 6);
  int lane = tid & 63;
  int h = lane >> 5;
  int l5 = lane & 31;
  int p0, p1;
  if (MODE == 0) { p0 = meta[d]; p1 = meta[d + 1]; }
  else           { p0 = d << CAP_LOG2; p1 = p0 + meta[d]; }
  int boff = l5 << 4;
  float acc[8] = {};
  int p = p0 + h;
  // 8-deep: load all metas first, then 8 independent 512B gathers in flight.
  for (; p + 14 < p1; p += 16) {
    int2 m[8];
#pragma unroll
    for (int q = 0; q < 8; ++q) m[q] = bkt[p + 2 * q];
    bf16x8 v[8];
#pragma unroll
    for (int q = 0; q < 8; ++q)
      v[q] = *(const bf16x8*)((const char*)(Tb + (((size_t)(m[q].x >> 16) * N_NODES_C + (m[q].x & 0xFFFF)) << 8)) + boff);
#pragma unroll
    for (int q = 0; q < 8; ++q) {
      float nq = __int_as_float(m[q].y);
#pragma unroll
      for (int j = 0; j < 8; ++j) acc[j] += (float)v[q][j] * nq;
    }
  }
  // 2-deep tail
  for (; p + 2 < p1; p += 4) {
    int2 m0 = bkt[p];
    int2 m1 = bkt[p + 2];
    bf16x8 v0 = *(const bf16x8*)((const char*)(Tb + (((size_t)(m0.x >> 16) * N_NODES_C + (m0.x & 0xFFFF)) << 8)) + boff);
    bf16x8 v1 = *(const bf16x8*)((const char*)(Tb + (((size_t)(m1.x >> 16) * N_NODES_C + (m1.x & 0xFFFF)) << 8)) + boff);
    float n0 = __int_as_float(m0.y);
    float n1 = __int_as_float(m1.y);
#pragma unroll
    for (int j = 0; j < 8; ++j) acc[j] += (float)v0[j] * n0 + (float)v1[j] * n1;
  }
  if (p < p1) {
    int2 m0 = bkt[p];
    bf16x8 v0 = *(const bf16x8*)((const char*)(Tb + (((size_t)(m0.x >> 16) * N_NODES_C + (m0.x & 0xFFFF)) << 8)) + boff);
    float n0 = __int_as_float(m0.y);
#pragma unroll
    for (int j = 0; j < 8; ++j) acc[j] += (float)v0[j] * n0;
  }
  float s[8];
#pragma unroll
  for (int j = 0; j < 8; ++j) {
    s[j] = acc[j];
    s[j] += __shfl_xor(s[j], 32);  // lanes l and l+32 hold same 8 cols of same dst
  }
  if (h == 0) {
    int g64 = (l5 >> 3) << 6;
    int lr4 = (l5 << 1) & 15;
    float* o = out + (size_t)d * FEAT_C + g64 + lr4;
#pragma unroll
    for (int j = 0; j < 4; ++j) {
      float2 w = { s[j], s[j + 4] };   // cols (g64 + j*16 + lr4, +1)
      *(float2*)(o + j * 16) = w;
    }
  }
}

extern "C" void kernel_launch(void* const* d_in, const int* in_sizes, int n_in,
                              void* d_out, int out_size, void* d_ws, size_t ws_size,
                              hipStream_t stream) {
  const float* h    = (const float*)d_in[0];
  const float* W    = (const float*)d_in[1];
  const float* norm = (const float*)d_in[2];
  const int*   src  = (const int*)d_in[3];
  const int*   dst  = (const int*)d_in[4];
  const int*   rel  = (const int*)d_in[5];
  float* out = (float*)d_out;

  char* ws = (char*)d_ws;
  bf16_t* hB   = (bf16_t*)ws;                          // 10,240,000 B
  bf16_t* Wt   = (bf16_t*)(ws + 10240000);             //  2,097,152 B
  bf16_t* Tb   = (bf16_t*)(ws + 12337152);             // 163,840,000 B -> 176,177,152

  if (ws_size >= WS_FAST_BYTES) {
    // ---- fast path: 3 dispatches ----
    int* cnt  = (int*)(ws + 176177152);                // 80,000 B
    int2* bkt = (int2*)(ws + 176257152);               // 10,240,000 B -> 186,497,152
    prep_fast_kernel<<<5335, 256, 0, stream>>>(h, hB, W, Wt, cnt);
    gemm_bucket_kernel<<<GEMM_BLOCKS + 1250, 256, 0, stream>>>(
        hB, Wt, Tb, dst, src, rel, norm, cnt, bkt);
    aggregate_kernel<1><<<5000, 256, 0, stream>>>(Tb, cnt, bkt, out);
  } else {
    // ---- slow path: known-good CSR chain ----
    int* dstart  = (int*)(ws + 176177152);             // 80,016 B
    int* dcur    = (int*)(ws + 176257168);             // 80,000 B
    int2* bkt    = (int2*)(ws + 176337168);            // 2,560,000 B -> ~178.9 MB
    hipMemsetAsync(dcur, 0, N_NODES_C * sizeof(int), stream);
    prep_kernel<<<10346, 256, 0, stream>>>(h, hB, W, Wt, dst, dcur);
    scan_dst_kernel<<<1, 256, 0, stream>>>(dcur, dstart);
    bucket_dst_kernel<<<1250, 256, 0, stream>>>(dst, src, rel, norm, dcur, bkt);
    gemm_bucket_kernel<<<GEMM_BLOCKS, 256, 0, stream>>>(
        hB, Wt, Tb, nullptr, nullptr, nullptr, nullptr, nullptr, nullptr);
    aggregate_kernel<0><<<5000, 256, 0, stream>>>(Tb, dstart, bkt, out);
  }
}